// Round 1
// baseline (220.845 us; speedup 1.0000x reference)
//
#include <hip/hip_runtime.h>
#include <math.h>

#define G      1708
#define GP     1728         // padded per-head row stride
#define C4     427          // float4 chunks per row
#define NH     5
#define NB     16
#define NC     34
#define JSL    32           // j-slices per i-group
#define ITR    3            // i rows per thread
#define IPB    24           // rows per block = (256/JSL)*ITR
#define ICH    72           // ceil(G/IPB)
#define LN_EPS 1e-6f
#define LOG2E  1.4426950408889634f

// ---------------------------------------------------------------------------
// prep_kernel: one block per (h,b).  For layers 2/3: recombine previous
// layer's per-head rows, LN, residual -> h row (written once by h==0 blocks).
// All blocks: k = h*WK*log2e, v = h*WV tables + per-(b,h) kmin/kmax.
// grid (NH, NB) = 80 blocks; removes all redundant phase-A/B work from the
// attention grid.
// ---------------------------------------------------------------------------
template <bool FIRST>
__global__ __launch_bounds__(256) void prep_kernel(
    const float* __restrict__ hprev, const float* __restrict__ php,
    const float* __restrict__ lna, const float* __restrict__ lnb,
    const float* __restrict__ WK, const float* __restrict__ WV,
    float* __restrict__ ktab, float* __restrict__ vtab,
    float* __restrict__ kmm, float* __restrict__ hcur)
{
    __shared__ float red[8];
    const int h = blockIdx.x, b = blockIdx.y, tid = threadIdx.x;
    const float4* hp4 = reinterpret_cast<const float4*>(hprev + (size_t)b * G);

    float4 acc[2];
    float mean = 0.f, inv = 0.f;
    if constexpr (!FIRST) {
        const float4* p0 = reinterpret_cast<const float4*>(php + ((size_t)b * NH + 0) * GP);
        const float4* p1 = reinterpret_cast<const float4*>(php + ((size_t)b * NH + 1) * GP);
        const float4* p2 = reinterpret_cast<const float4*>(php + ((size_t)b * NH + 2) * GP);
        const float4* p3 = reinterpret_cast<const float4*>(php + ((size_t)b * NH + 3) * GP);
        const float4* p4 = reinterpret_cast<const float4*>(php + ((size_t)b * NH + 4) * GP);
        float s = 0.f, ss = 0.f;
#pragma unroll
        for (int it = 0; it < 2; ++it) {
            const int c = tid + it * 256;
            if (c < C4) {
                float4 a = p0[c], t;
                t = p1[c]; a.x += t.x; a.y += t.y; a.z += t.z; a.w += t.w;
                t = p2[c]; a.x += t.x; a.y += t.y; a.z += t.z; a.w += t.w;
                t = p3[c]; a.x += t.x; a.y += t.y; a.z += t.z; a.w += t.w;
                t = p4[c]; a.x += t.x; a.y += t.y; a.z += t.z; a.w += t.w;
                acc[it] = a;
                s  += (a.x + a.y) + (a.z + a.w);
                ss += (a.x * a.x + a.y * a.y) + (a.z * a.z + a.w * a.w);
            }
        }
        for (int o = 1; o < 64; o <<= 1) {
            s  += __shfl_xor(s, o);
            ss += __shfl_xor(ss, o);
        }
        if ((tid & 63) == 0) { red[tid >> 6] = s; red[4 + (tid >> 6)] = ss; }
        __syncthreads();
        float S  = (red[0] + red[1]) + (red[2] + red[3]);
        float SS = (red[4] + red[5]) + (red[6] + red[7]);
        mean = S / (float)G;
        float var = fmaxf((SS - S * mean) / (float)(G - 1), 0.f);
        inv = 1.f / (sqrtf(var) + LN_EPS);
        __syncthreads();   // red reads done before minmax reuse
    }

    const float4* ga4 = reinterpret_cast<const float4*>(lna);
    const float4* gb4 = reinterpret_cast<const float4*>(lnb);
    const float4* wk4 = reinterpret_cast<const float4*>(WK + (size_t)h * G);
    const float4* wv4 = reinterpret_cast<const float4*>(WV + (size_t)h * G);
    const size_t pbh = (size_t)b * NH + h;
    float4* kt4 = reinterpret_cast<float4*>(ktab + pbh * GP);
    float4* vt4 = reinterpret_cast<float4*>(vtab + pbh * GP);
    float4* hc4 = (!FIRST && h == 0)
                      ? reinterpret_cast<float4*>(hcur + (size_t)b * G) : nullptr;

    float kmx = -INFINITY, kmn = INFINITY;
#pragma unroll
    for (int it = 0; it < 2; ++it) {
        const int c = tid + it * 256;
        if (c < C4) {
            float4 hv;
            if constexpr (FIRST) {
                hv = hp4[c];
            } else {
                float4 a = acc[it], hp = hp4[c], ga = ga4[c], gb = gb4[c];
                hv.x = hp.x + ga.x * (a.x - mean) * inv + gb.x;
                hv.y = hp.y + ga.y * (a.y - mean) * inv + gb.y;
                hv.z = hp.z + ga.z * (a.z - mean) * inv + gb.z;
                hv.w = hp.w + ga.w * (a.w - mean) * inv + gb.w;
            }
            if (hc4) hc4[c] = hv;
            float4 wk = wk4[c], wv = wv4[c], kl, vv;
            kl.x = hv.x * wk.x * LOG2E; kl.y = hv.y * wk.y * LOG2E;
            kl.z = hv.z * wk.z * LOG2E; kl.w = hv.w * wk.w * LOG2E;
            vv.x = hv.x * wv.x; vv.y = hv.y * wv.y;
            vv.z = hv.z * wv.z; vv.w = hv.w * wv.w;
            kt4[c] = kl;
            vt4[c] = vv;
            kmx = fmaxf(kmx, fmaxf(fmaxf(kl.x, kl.y), fmaxf(kl.z, kl.w)));
            kmn = fminf(kmn, fminf(fminf(kl.x, kl.y), fminf(kl.z, kl.w)));
        }
    }
    for (int o = 1; o < 64; o <<= 1) {
        kmx = fmaxf(kmx, __shfl_xor(kmx, o));
        kmn = fminf(kmn, __shfl_xor(kmn, o));
    }
    if ((tid & 63) == 0) { red[tid >> 6] = kmx; red[4 + (tid >> 6)] = kmn; }
    __syncthreads();
    if (tid == 0) {
        kmm[pbh * 2 + 0] = fmaxf(fmaxf(red[0], red[1]), fmaxf(red[2], red[3]));
        kmm[pbh * 2 + 1] = fminf(fminf(red[4], red[5]), fminf(red[6], red[7]));
    }
}

// ---------------------------------------------------------------------------
// attn_kernel: pure phase-C.  Stage k/v tables (13.7 KB LDS) from global,
// then softmax-weighted sums over j.  grid (72,5,16) = 5760 blocks;
// __launch_bounds__(256,8) pins VGPR<=64 so 8 blocks/CU (wave cap) are
// resident -> 2048 concurrent -> 5760/2048 = 2.81 -> 3 rounds at 94% fill.
// ---------------------------------------------------------------------------
__global__ __launch_bounds__(256, 8) void attn_kernel(
    const float* __restrict__ hsrc, const float* __restrict__ WQ,
    const float* __restrict__ ktab, const float* __restrict__ vtab,
    const float* __restrict__ kmm, const float* __restrict__ W0,
    float* __restrict__ ph)
{
    __shared__ __align__(16) float krow[G];
    __shared__ __align__(16) float vrow[G];
    const int ic = blockIdx.x, h = blockIdx.y, b = blockIdx.z;
    const int tid = threadIdx.x;
    const size_t pbh = (size_t)b * NH + h;

    const float4* kt4 = reinterpret_cast<const float4*>(ktab + pbh * GP);
    const float4* vt4 = reinterpret_cast<const float4*>(vtab + pbh * GP);
    float4* kr4 = reinterpret_cast<float4*>(krow);
    float4* vr4 = reinterpret_cast<float4*>(vrow);
    for (int c = tid; c < C4; c += 256) { kr4[c] = kt4[c]; vr4[c] = vt4[c]; }

    // overlap scalar setup with staging (before the barrier)
    const float kmx = kmm[pbh * 2 + 0];
    const float kmn = kmm[pbh * 2 + 1];
    const float w0h = W0[h];
    const int ig = tid >> 5, sl = tid & 31;
    const int i0 = ic * IPB + ig * ITR;
    const float* hb = hsrc + (size_t)b * G;
    const float* wq = WQ + (size_t)h * G;

    float q[ITR], m[ITR], S1[ITR], S2[ITR];
#pragma unroll
    for (int r = 0; r < ITR; ++r) {
        const int row = i0 + r;
        const int rs = row < G ? row : 0;
        q[r]  = hb[rs] * wq[rs];
        m[r]  = fmaxf(q[r] * kmx, q[r] * kmn);   // exact rank-1 row max bound
        S1[r] = 0.f;
        S2[r] = 0.f;
    }
    __syncthreads();

#pragma unroll 2
    for (int c = sl; c < C4; c += JSL) {
        const float4 kk = kr4[c];
        const float4 vv = vr4[c];
#pragma unroll
        for (int r = 0; r < ITR; ++r) {
            const float qq = q[r], mm = m[r];
            float e0 = __builtin_amdgcn_exp2f(fmaf(qq, kk.x, -mm));
            float e1 = __builtin_amdgcn_exp2f(fmaf(qq, kk.y, -mm));
            float e2 = __builtin_amdgcn_exp2f(fmaf(qq, kk.z, -mm));
            float e3 = __builtin_amdgcn_exp2f(fmaf(qq, kk.w, -mm));
            S1[r] += (e0 + e1) + (e2 + e3);
            S2[r] = fmaf(e0, vv.x, S2[r]);
            S2[r] = fmaf(e1, vv.y, S2[r]);
            S2[r] = fmaf(e2, vv.z, S2[r]);
            S2[r] = fmaf(e3, vv.w, S2[r]);
        }
    }

#pragma unroll
    for (int r = 0; r < ITR; ++r) {
        S1[r] += __shfl_xor(S1[r], 1);
        S1[r] += __shfl_xor(S1[r], 2);
        S1[r] += __shfl_xor(S1[r], 4);
        S1[r] += __shfl_xor(S1[r], 8);
        S1[r] += __shfl_xor(S1[r], 16);
        S2[r] += __shfl_xor(S2[r], 1);
        S2[r] += __shfl_xor(S2[r], 2);
        S2[r] += __shfl_xor(S2[r], 4);
        S2[r] += __shfl_xor(S2[r], 8);
        S2[r] += __shfl_xor(S2[r], 16);
    }

    if (sl == 0) {
        float* pout = ph + pbh * GP;
#pragma unroll
        for (int r = 0; r < ITR; ++r) {
            const int row = i0 + r;
            if (row < G) {
                float eii = __builtin_amdgcn_exp2f(fmaf(q[r], krow[row], -m[r]));
                pout[row] = w0h * (S2[r] - eii * vrow[row]) / S1[r];
            }
        }
    }
}

// ---------------------------------------------------------------------------
// One logit per block: recombine layer-3 heads + LN on the fly, dot with
// fc row c.  grid (NC, NB) = 544 blocks.  (unchanged)
// ---------------------------------------------------------------------------
__global__ __launch_bounds__(256) void logits_kernel(
    const float* __restrict__ hprev, const float* __restrict__ php,
    const float* __restrict__ lna, const float* __restrict__ lnb,
    const float* __restrict__ fcw, const float* __restrict__ fcb,
    float* __restrict__ lgt)
{
    __shared__ __align__(16) float arow[G];
    __shared__ float red[8];
    const int c = blockIdx.x, b = blockIdx.y, tid = threadIdx.x;

    const float4* p0 = reinterpret_cast<const float4*>(php + ((size_t)b * NH + 0) * GP);
    const float4* p1 = reinterpret_cast<const float4*>(php + ((size_t)b * NH + 1) * GP);
    const float4* p2 = reinterpret_cast<const float4*>(php + ((size_t)b * NH + 2) * GP);
    const float4* p3 = reinterpret_cast<const float4*>(php + ((size_t)b * NH + 3) * GP);
    const float4* p4 = reinterpret_cast<const float4*>(php + ((size_t)b * NH + 4) * GP);
    float4* ar4 = reinterpret_cast<float4*>(arow);

    float s = 0.f, ss = 0.f;
    for (int k = tid; k < C4; k += 256) {
        float4 a = p0[k], t;
        t = p1[k]; a.x += t.x; a.y += t.y; a.z += t.z; a.w += t.w;
        t = p2[k]; a.x += t.x; a.y += t.y; a.z += t.z; a.w += t.w;
        t = p3[k]; a.x += t.x; a.y += t.y; a.z += t.z; a.w += t.w;
        t = p4[k]; a.x += t.x; a.y += t.y; a.z += t.z; a.w += t.w;
        ar4[k] = a;
        s  += (a.x + a.y) + (a.z + a.w);
        ss += (a.x * a.x + a.y * a.y) + (a.z * a.z + a.w * a.w);
    }
    for (int o = 1; o < 64; o <<= 1) {
        s  += __shfl_xor(s, o);
        ss += __shfl_xor(ss, o);
    }
    if ((tid & 63) == 0) { red[tid >> 6] = s; red[4 + (tid >> 6)] = ss; }
    __syncthreads();
    float S  = (red[0] + red[1]) + (red[2] + red[3]);
    float SS = (red[4] + red[5]) + (red[6] + red[7]);
    const float mean = S / (float)G;
    const float var  = fmaxf((SS - S * mean) / (float)(G - 1), 0.f);
    const float inv  = 1.f / (sqrtf(var) + LN_EPS);

    const float4* hp4 = reinterpret_cast<const float4*>(hprev + (size_t)b * G);
    const float4* ga4 = reinterpret_cast<const float4*>(lna);
    const float4* gb4 = reinterpret_cast<const float4*>(lnb);
    const float4* w4  = reinterpret_cast<const float4*>(fcw + (size_t)c * G);
    float acc = 0.f;
    for (int k = tid; k < C4; k += 256) {
        float4 a = ar4[k], hp = hp4[k], ga = ga4[k], gb = gb4[k], w = w4[k];
        float hx = hp.x + ga.x * (a.x - mean) * inv + gb.x;
        float hy = hp.y + ga.y * (a.y - mean) * inv + gb.y;
        float hz = hp.z + ga.z * (a.z - mean) * inv + gb.z;
        float hw = hp.w + ga.w * (a.w - mean) * inv + gb.w;
        acc += (hx * w.x + hy * w.y) + (hz * w.z + hw * w.w);
    }
    for (int o = 1; o < 64; o <<= 1) acc += __shfl_xor(acc, o);
    __syncthreads();
    if ((tid & 63) == 0) red[tid >> 6] = acc;
    __syncthreads();
    if (tid == 0)
        lgt[(size_t)b * NC + c] =
            (red[0] + red[1]) + (red[2] + red[3]) + fcb[c];
}

// out = log_softmax(logits) — one wave per batch row  (unchanged)
__global__ __launch_bounds__(64) void lsm_kernel(
    const float* __restrict__ lgt, float* __restrict__ out)
{
    const int b = blockIdx.x, tid = threadIdx.x;
    float l = (tid < NC) ? lgt[(size_t)b * NC + tid] : -INFINITY;
    float mm = l;
    for (int o = 32; o; o >>= 1) mm = fmaxf(mm, __shfl_xor(mm, o));
    float e = (tid < NC) ? expf(l - mm) : 0.f;
    float se = e;
    for (int o = 32; o; o >>= 1) se += __shfl_xor(se, o);
    if (tid < NC) out[(size_t)b * NC + tid] = l - mm - logf(se);
}

// ---------------------------------------------------------------------------
extern "C" void kernel_launch(void* const* d_in, const int* in_sizes, int n_in,
                              void* d_out, int out_size, void* d_ws, size_t ws_size,
                              hipStream_t stream)
{
    const float* x    = (const float*)d_in[0];
    const float* WQ1  = (const float*)d_in[1];
    const float* WK1  = (const float*)d_in[2];
    const float* WV1  = (const float*)d_in[3];
    const float* W01  = (const float*)d_in[4];
    const float* WQ2  = (const float*)d_in[5];
    const float* WK2  = (const float*)d_in[6];
    const float* WV2  = (const float*)d_in[7];
    const float* W02  = (const float*)d_in[8];
    const float* WQ3  = (const float*)d_in[9];
    const float* WK3  = (const float*)d_in[10];
    const float* WV3  = (const float*)d_in[11];
    const float* W03  = (const float*)d_in[12];
    const float* lna  = (const float*)d_in[13];
    const float* lnb  = (const float*)d_in[14];
    const float* fcw  = (const float*)d_in[15];
    const float* fcb  = (const float*)d_in[16];
    float* out = (float*)d_out;

    const size_t PHS = (size_t)NB * NH * GP;
    float* pha  = (float*)d_ws;                 // layer 1 / 3 per-head rows
    float* phb  = pha + PHS;                    // layer 2 per-head rows
    float* ktab = phb + PHS;                    // [NB,NH,GP] k*log2e
    float* vtab = ktab + PHS;                   // [NB,NH,GP] v
    float* h1   = vtab + PHS;                   // [NB,G] layer-3 input
    float* h2   = h1 + (size_t)NB * G;          // [NB,G] logits-LN input
    float* kmm  = h2 + (size_t)NB * G;          // [NB,NH,2] kmax/kmin
    float* lgt  = kmm + (size_t)NB * NH * 2;    // [NB,NC]

    const dim3 pgrid(NH, NB);                   // 80 blocks
    const dim3 agrid(ICH, NH, NB);              // (72,5,16) = 5760 blocks

    prep_kernel<true><<<pgrid, 256, 0, stream>>>(
        x, nullptr, lna, lnb, WK1, WV1, ktab, vtab, kmm, nullptr);
    attn_kernel<<<agrid, 256, 0, stream>>>(
        x, WQ1, ktab, vtab, kmm, W01, pha);

    prep_kernel<false><<<pgrid, 256, 0, stream>>>(
        x, pha, lna, lnb, WK2, WV2, ktab, vtab, kmm, h1);
    attn_kernel<<<agrid, 256, 0, stream>>>(
        h1, WQ2, ktab, vtab, kmm, W02, phb);

    prep_kernel<false><<<pgrid, 256, 0, stream>>>(
        h1, phb, lna, lnb, WK3, WV3, ktab, vtab, kmm, h2);
    attn_kernel<<<agrid, 256, 0, stream>>>(
        h2, WQ3, ktab, vtab, kmm, W03, pha);

    logits_kernel<<<dim3(NC, NB), 256, 0, stream>>>(
        h2, pha, lna, lnb, fcw, fcb, lgt);
    lsm_kernel<<<NB, 64, 0, stream>>>(lgt, out);
}